// Round 11
// baseline (200.634 us; speedup 1.0000x reference)
//
#include <hip/hip_runtime.h>
#include <stdint.h>

typedef unsigned short u16;
typedef short bf16x8 __attribute__((ext_vector_type(8)));
typedef bf16x8 __attribute__((may_alias)) bf16x8_a;
typedef unsigned u32x2 __attribute__((ext_vector_type(2)));
typedef u32x2 __attribute__((may_alias)) u32x2_a;
typedef float f32x4 __attribute__((ext_vector_type(4)));
typedef f32x4 __attribute__((may_alias)) f32x4_a;

#define BATCH 8
#define HEADS 16
#define SEQ 1024
#define HD 64
#define NB 32
#define LOG2E 1.44269504f
#define MBIAS 46.16624128f          // 32 * log2(e): static softmax max-bound
// unified packed block per (bh, j): [0,2048) K hi | [2048,4096) K lo | [4096,6144) V^T
// each section: 4 frags x (64 lanes x 8 u16) -- 12KB contiguous per KV-block visit
#define PBLK 6144

__device__ unsigned g_bm[HEADS * NB];                        // active-block bitmask per (h, i32)
__device__ u16 g_pack[(size_t)BATCH * HEADS * NB * PBLK];    // unified K hi/lo + V^T

__device__ __forceinline__ u16 f2bf(float x) {
    unsigned u = __builtin_bit_cast(unsigned, x);
    u += 0x7fffu + ((u >> 16) & 1u);   // RNE
    return (u16)(u >> 16);
}
__device__ __forceinline__ float bf2f(u16 h) {
    unsigned u = ((unsigned)h) << 16;
    return __builtin_bit_cast(float, u);
}
__device__ __forceinline__ bf16x8 pack8(float4 a, float4 b) {
    bf16x8 r;
    r[0] = (short)f2bf(a.x); r[1] = (short)f2bf(a.y);
    r[2] = (short)f2bf(a.z); r[3] = (short)f2bf(a.w);
    r[4] = (short)f2bf(b.x); r[5] = (short)f2bf(b.y);
    r[6] = (short)f2bf(b.z); r[7] = (short)f2bf(b.w);
    return r;
}
__device__ __forceinline__ bf16x8 pack8_res(float4 a, float4 b, bf16x8 hi) {
    bf16x8 r;
    r[0] = (short)f2bf(a.x - bf2f((u16)hi[0])); r[1] = (short)f2bf(a.y - bf2f((u16)hi[1]));
    r[2] = (short)f2bf(a.z - bf2f((u16)hi[2])); r[3] = (short)f2bf(a.w - bf2f((u16)hi[3]));
    r[4] = (short)f2bf(b.x - bf2f((u16)hi[4])); r[5] = (short)f2bf(b.y - bf2f((u16)hi[5]));
    r[6] = (short)f2bf(b.z - bf2f((u16)hi[6])); r[7] = (short)f2bf(b.w - bf2f((u16)hi[7]));
    return r;
}

// ---------------- fused prep (all paths COALESCED both directions) ----------------
// blocks 0..4095      : K hi/lo frag-pack via LDS bounce (read coal -> LDS -> store coal)
// blocks 4096..6143   : V^T frag-pack (32-row LDS tile, 2 passes; coalesced stores)
// blocks 6144..6159   : block-mask words (one per head)
__global__ __launch_bounds__(256) void prep_kv(const float* __restrict__ k,
                                               const float* __restrict__ v,
                                               const float* __restrict__ mask) {
    int bid = blockIdx.x;
    int t = threadIdx.x;
    if (bid < 4096) {
        __shared__ u16 lk[2][2048];
        // coalesced read: thread t covers bytes t*32..t*32+31 of the 8KB f32 block
        int bh = bid >> 5, j = bid & 31;
        int row = t >> 3, dg = t & 7;
        const float* s = k + ((size_t)(bh * SEQ + j * 32 + row)) * HD + dg * 8;
        float4 a = *(const float4*)(s);
        float4 b = *(const float4*)(s + 4);
        bf16x8 hi = pack8(a, b);
        bf16x8 lo = pack8_res(a, b, hi);
        int c = ((row >> 4) << 1) + (dg >> 2);
        int lane = (row & 15) + ((dg & 3) << 4);
        int o16 = c * 512 + lane * 8;
        *(bf16x8_a*)(&lk[0][o16]) = hi;
        *(bf16x8_a*)(&lk[1][o16]) = lo;
        __syncthreads();
        // coalesced store: thread t writes flat elems t*8 of hi and lo sections
        u16* dst = g_pack + ((size_t)(bh * NB + j)) * PBLK + t * 8;
        *(uint4*)dst = *(const uint4*)&lk[0][t * 8];
        *(uint4*)(dst + 2048) = *(const uint4*)&lk[1][t * 8];
        return;
    }
    if (bid < 6144) {
        __shared__ float tile[32 * 65];
        // V transpose + bf16, A-fragment order: A[d = c*16 + (lane&15)][key = (lane>>4)*8 + e]
        int tb = bid - 4096;                      // 2048 = 128 bh * 16 ktiles(64)
        int bh = tb >> 4, kt = tb & 15;
        const float* src = v + ((size_t)(bh * SEQ + kt * 64)) * HD;
#pragma unroll
        for (int pass = 0; pass < 2; ++pass) {
#pragma unroll
            for (int p = 0; p < 2; ++p) {
                int row = p * 16 + (t >> 4);              // 0..31 within pass
                int col = (t & 15) * 4;
                float4 d = *(const float4*)(src + (size_t)(pass * 32 + row) * HD + col);
                float* tp = &tile[row * 65 + col];
                tp[0] = d.x; tp[1] = d.y; tp[2] = d.z; tp[3] = d.w;
            }
            __syncthreads();
            {
                // coalesced store map: thread t -> flat elem t*8 of the V^T section.
                int c = t >> 6;
                int lane = t & 63;
                int dd = (c << 4) + (lane & 15);
                int kc = (lane >> 4) * 8;
                u16 tmp[8];
#pragma unroll
                for (int i = 0; i < 8; ++i) tmp[i] = f2bf(tile[(kc + i) * 65 + dd]);
                int j = kt * 2 + pass;
                size_t o = ((size_t)(bh * NB + j)) * PBLK + 4096 + (size_t)t * 8;
                *(uint4*)(g_pack + o) = *(const uint4*)tmp;
            }
            __syncthreads();
        }
        return;
    }
    // block-mask path: 16 blocks, one head each; 256 threads sweep 1024 (i,j) pairs
    int h = bid - 6144;
    int lane = t & 63;
#pragma unroll
    for (int kk2 = 0; kk2 < 4; ++kk2) {
        int tt = (kk2 << 8) | t;                  // 0..1023
        int i = tt >> 5, j = tt & 31;
        float mv = mask[(size_t)h * SEQ * SEQ + (size_t)(i * 32) * SEQ + (size_t)(j * 32)];
        bool pred = (j == i) || (j < i && mv != 0.0f);
        unsigned long long bal = __ballot(pred);
        if (lane == 0)  g_bm[h * NB + i] = (unsigned)(bal & 0xffffffffull);
        if (lane == 32) g_bm[h * NB + i] = (unsigned)(bal >> 32);
    }
}

// ---------------- attention building blocks ----------------
__device__ __forceinline__ void load_blk(size_t pb, bf16x8 (&kh)[4], bf16x8 (&kl)[4],
                                         bf16x8 (&vf)[4]) {
#pragma unroll
    for (int c = 0; c < 4; ++c) {
        kh[c] = *(const bf16x8_a*)(const void*)(g_pack + pb + c * 512);
        kl[c] = *(const bf16x8_a*)(const void*)(g_pack + pb + 2048 + c * 512);
        vf[c] = *(const bf16x8_a*)(const void*)(g_pack + pb + 4096 + c * 512);
    }
}

__device__ __forceinline__ void compute_blk(int j, int i32, int qcol, int quad,
                                            const bf16x8 (&kh)[4], const bf16x8 (&kl)[4],
                                            const bf16x8 (&vf)[4],
                                            const bf16x8 (&qh)[2][2], const bf16x8 (&ql)[2][2],
                                            u16* pl, f32x4 (&oacc)[2][4], float& l0, float& l1) {
    // T = K*Q^T, split-bf16; tt[kt][t]: keys kt*16+quad*4+r, q = t*16+qcol
    f32x4 tt[2][2];
    __builtin_amdgcn_s_setprio(1);
#pragma unroll
    for (int kt = 0; kt < 2; ++kt)
#pragma unroll
        for (int t = 0; t < 2; ++t) {
            f32x4 acc = f32x4{0.f, 0.f, 0.f, 0.f};
            acc = __builtin_amdgcn_mfma_f32_16x16x32_bf16(kl[kt*2+0], qh[t][0], acc, 0, 0, 0);
            acc = __builtin_amdgcn_mfma_f32_16x16x32_bf16(kl[kt*2+1], qh[t][1], acc, 0, 0, 0);
            acc = __builtin_amdgcn_mfma_f32_16x16x32_bf16(kh[kt*2+0], ql[t][0], acc, 0, 0, 0);
            acc = __builtin_amdgcn_mfma_f32_16x16x32_bf16(kh[kt*2+1], ql[t][1], acc, 0, 0, 0);
            acc = __builtin_amdgcn_mfma_f32_16x16x32_bf16(kh[kt*2+0], qh[t][0], acc, 0, 0, 0);
            acc = __builtin_amdgcn_mfma_f32_16x16x32_bf16(kh[kt*2+1], qh[t][1], acc, 0, 0, 0);
            tt[kt][t] = acc;
        }
    __builtin_amdgcn_s_setprio(0);

    if (j == i32) {  // diagonal block: causal within 32x32
#pragma unroll
        for (int kt = 0; kt < 2; ++kt)
#pragma unroll
            for (int t = 0; t < 2; ++t)
#pragma unroll
                for (int r = 0; r < 4; ++r) {
                    int key = kt * 16 + quad * 4 + r;
                    if (key > t * 16 + qcol) tt[kt][t][r] = -1e30f;
                }
    }

    // static-max softmax: p = exp2(s*log2e - 32*log2e); no reductions in loop
    u16 pb[2][8];
#pragma unroll
    for (int kt = 0; kt < 2; ++kt)
#pragma unroll
        for (int t = 0; t < 2; ++t) {
            float psum = 0.f;
#pragma unroll
            for (int r = 0; r < 4; ++r) {
                float e = exp2f(tt[kt][t][r] * LOG2E - MBIAS);
                u16 eb = f2bf(e);
                pb[t][kt * 4 + r] = eb;
                psum += bf2f(eb);      // sum ROUNDED p: out = sum(p_hat v)/sum(p_hat)
            }
            if (t == 0) l0 += psum; else l1 += psum;
        }

    // P^T relayout through LDS (same-wave DS ops in order; may_alias preserves ordering)
#pragma unroll
    for (int t = 0; t < 2; ++t)
#pragma unroll
        for (int kt = 0; kt < 2; ++kt) {
            u32x2 pw;
            pw[0] = (unsigned)pb[t][kt*4+0] | ((unsigned)pb[t][kt*4+1] << 16);
            pw[1] = (unsigned)pb[t][kt*4+2] | ((unsigned)pb[t][kt*4+3] << 16);
            *(u32x2_a*)(pl + (t * 16 + qcol) * 40 + kt * 16 + quad * 4) = pw;
        }
    bf16x8 pf0 = *(const bf16x8_a*)(pl + qcol * 40 + quad * 8);
    bf16x8 pf1 = *(const bf16x8_a*)(pl + (16 + qcol) * 40 + quad * 8);

    __builtin_amdgcn_s_setprio(1);
#pragma unroll
    for (int c = 0; c < 4; ++c) {
        oacc[0][c] = __builtin_amdgcn_mfma_f32_16x16x32_bf16(vf[c], pf0, oacc[0][c], 0, 0, 0);
        oacc[1][c] = __builtin_amdgcn_mfma_f32_16x16x32_bf16(vf[c], pf1, oacc[1][c], 0, 0, 0);
    }
    __builtin_amdgcn_s_setprio(0);
}

// ---------------- block-sparse causal flash attention ----------------
// r11: ONE WAVE per (bh, i32) row-block. Two targeted fixes to the measured
// tau_visit ~= 2.5us (= 12 loads x L3 latency, SERIALIZED -- r10 arithmetic):
// (1) batch load issue: single-buffer load_blk followed by a compiler memory
//     barrier (asm "":::"memory") -- the 12 independent loads cannot sink to
//     their use sites, so the visit pays ONE memory latency, not twelve.
// (2) LDS padded to 16384B -> 10 blocks/CU residency cap. r10's full-grid
//     co-residency (16/CU) put all 16 bh live per XCD (6MB > 4MB L2, thrash)
//     and disabled LPT backfill. At 10/CU the live set ~= one 8-bh half-group
//     (3.8MB, L2-fits) and heavy-first dispatch backfills properly.
// Dispatch: slot = bid&7 == bh&7 pins bh to one XCD; two 8-bh half-groups per
// XCD; i32 descending (heavy-first LPT).
__global__ __launch_bounds__(64, 2) void attn(const float* __restrict__ q,
                                              float* __restrict__ out) {
    __shared__ __align__(16) char smem[16384];   // P (2560B) / O staging; padded: residency cap

    int lane = threadIdx.x & 63;
    int qcol = lane & 15;
    int quad = lane >> 4;

    int bid = blockIdx.x;
    int slot = bid & 7;                 // XCD
    int r = bid >> 3;                   // 0..511 per slot
    int half = r >> 8;                  // 8-bh group
    int rr = r & 255;
    int i32 = 31 - (rr >> 3);           // heavy rows dispatched first within group
    int bh = slot + ((((half << 3) | (rr & 7))) << 3);   // bh&7 == slot
    int h = bh & (HEADS - 1);

    // Q fragments (B-operand): X[q=qcol][d = quad*8 + dh*32 + e], per q-tile t
    bf16x8 qh[2][2], ql[2][2];
#pragma unroll
    for (int t = 0; t < 2; ++t) {
        const float* qb = q + ((size_t)(bh * SEQ + i32 * 32 + t * 16 + qcol)) * HD + quad * 8;
#pragma unroll
        for (int dh = 0; dh < 2; ++dh) {
            float4 a = *(const float4*)(qb + dh * 32);
            float4 b = *(const float4*)(qb + dh * 32 + 4);
            qh[t][dh] = pack8(a, b);
            ql[t][dh] = pack8_res(a, b, qh[t][dh]);
        }
    }

    unsigned bits = g_bm[h * NB + i32];
    size_t bhbase = (size_t)bh * NB * PBLK + lane * 8;
    u16* pl = (u16*)smem;

    f32x4 oacc[2][4];
#pragma unroll
    for (int t = 0; t < 2; ++t)
#pragma unroll
        for (int c = 0; c < 4; ++c) oacc[t][c] = f32x4{0.f, 0.f, 0.f, 0.f};
    float l0 = 0.f, l1 = 0.f;

    // per-visit: batch-issue 12 loads, barrier pins issue point, compute waits at use
    unsigned rem = bits;
    while (rem) {
        int j = __builtin_ctz(rem); rem &= rem - 1;
        bf16x8 kh[4], kl[4], vf[4];
        load_blk(bhbase + (size_t)j * PBLK, kh, kl, vf);
        asm volatile("" ::: "memory");   // loads may not sink past this point
        compute_blk(j, i32, qcol, quad, kh, kl, vf, qh, ql, pl, oacc, l0, l1);
    }

    // l reduction: after butterfly, l0/l1 hold the per-q-row denominator (per qcol)
    l0 += __shfl_xor(l0, 16); l0 += __shfl_xor(l0, 32);
    l1 += __shfl_xor(l1, 16); l1 += __shfl_xor(l1, 32);
    float inv[2] = {1.0f / l0, 1.0f / l1};

    // O = oacc / l staged via LDS for dense 1KB stores (same-wave DS ordering)
    float* ol = (float*)smem;             // 32 rows x 64 d, stride 68 floats
#pragma unroll
    for (int t = 0; t < 2; ++t)
#pragma unroll
        for (int c = 0; c < 4; ++c) {
            f32x4 val;
            val[0] = oacc[t][c][0] * inv[t]; val[1] = oacc[t][c][1] * inv[t];
            val[2] = oacc[t][c][2] * inv[t]; val[3] = oacc[t][c][3] * inv[t];
            *(f32x4_a*)(ol + (t * 16 + qcol) * 68 + c * 16 + quad * 4) = val;
        }
    // dense output: per instr 64 lanes cover 4 rows x 256B = 1KB contiguous
    float* obase = out + ((size_t)(bh * SEQ + i32 * 32)) * HD;
#pragma unroll
    for (int gr = 0; gr < 8; ++gr) {
        int row = gr * 4 + (lane >> 4);
        int colf = (lane & 15) * 4;
        f32x4 val = *(const f32x4_a*)(ol + row * 68 + colf);
        *(float4*)(obase + (size_t)row * HD + colf) = make_float4(val[0], val[1], val[2], val[3]);
    }
}

extern "C" void kernel_launch(void* const* d_in, const int* in_sizes, int n_in,
                              void* d_out, int out_size, void* d_ws, size_t ws_size,
                              hipStream_t stream) {
    const float* q = (const float*)d_in[0];
    const float* k = (const float*)d_in[1];
    const float* v = (const float*)d_in[2];
    const float* mask = (const float*)d_in[3];
    float* out = (float*)d_out;

    prep_kv<<<4096 + 2048 + 16, 256, 0, stream>>>(k, v, mask);
    attn<<<4096, 64, 0, stream>>>(q, out);
}

// Round 12
// 191.527 us; speedup vs baseline: 1.0475x; 1.0475x over previous
//
#include <hip/hip_runtime.h>
#include <stdint.h>

typedef unsigned short u16;
typedef short bf16x8 __attribute__((ext_vector_type(8)));
typedef bf16x8 __attribute__((may_alias)) bf16x8_a;
typedef unsigned u32x2 __attribute__((ext_vector_type(2)));
typedef u32x2 __attribute__((may_alias)) u32x2_a;
typedef float f32x4 __attribute__((ext_vector_type(4)));
typedef f32x4 __attribute__((may_alias)) f32x4_a;

#define BATCH 8
#define HEADS 16
#define SEQ 1024
#define HD 64
#define NB 32
#define LOG2E 1.44269504f
#define MBIAS 46.16624128f          // 32 * log2(e): static softmax max-bound
// unified packed block per (bh, j): [0,2048) K bf16 | [2048,4096) V^T bf16
// each section: 4 frags x (64 lanes x 8 u16) -- 8KB contiguous per KV-block visit.
// K-lo residual DROPPED (r12): Q keeps hi/lo split; K single bf16. Error budget:
// absmax 0.031 vs threshold 0.104 (3.3x headroom); softmax normalization cancels
// the common-mode score shift, expected absmax ~0.05-0.08.
#define PBLK 4096

__device__ unsigned g_bm[HEADS * NB];                        // active-block bitmask per (h, i32)
__device__ u16 g_pack[(size_t)BATCH * HEADS * NB * PBLK];    // unified K bf16 + V^T

__device__ __forceinline__ u16 f2bf(float x) {
    unsigned u = __builtin_bit_cast(unsigned, x);
    u += 0x7fffu + ((u >> 16) & 1u);   // RNE
    return (u16)(u >> 16);
}
__device__ __forceinline__ float bf2f(u16 h) {
    unsigned u = ((unsigned)h) << 16;
    return __builtin_bit_cast(float, u);
}
__device__ __forceinline__ bf16x8 pack8(float4 a, float4 b) {
    bf16x8 r;
    r[0] = (short)f2bf(a.x); r[1] = (short)f2bf(a.y);
    r[2] = (short)f2bf(a.z); r[3] = (short)f2bf(a.w);
    r[4] = (short)f2bf(b.x); r[5] = (short)f2bf(b.y);
    r[6] = (short)f2bf(b.z); r[7] = (short)f2bf(b.w);
    return r;
}
__device__ __forceinline__ bf16x8 pack8_res(float4 a, float4 b, bf16x8 hi) {
    bf16x8 r;
    r[0] = (short)f2bf(a.x - bf2f((u16)hi[0])); r[1] = (short)f2bf(a.y - bf2f((u16)hi[1]));
    r[2] = (short)f2bf(a.z - bf2f((u16)hi[2])); r[3] = (short)f2bf(a.w - bf2f((u16)hi[3]));
    r[4] = (short)f2bf(b.x - bf2f((u16)hi[4])); r[5] = (short)f2bf(b.y - bf2f((u16)hi[5]));
    r[6] = (short)f2bf(b.z - bf2f((u16)hi[6])); r[7] = (short)f2bf(b.w - bf2f((u16)hi[7]));
    return r;
}

// ---------------- fused prep (all paths COALESCED both directions) ----------------
// blocks 0..4095      : K bf16 frag-pack via LDS bounce (read coal -> LDS -> store coal)
// blocks 4096..6143   : V^T frag-pack (32-row LDS tile, 2 passes; coalesced stores)
// blocks 6144..6159   : block-mask words (one per head)
__global__ __launch_bounds__(256) void prep_kv(const float* __restrict__ k,
                                               const float* __restrict__ v,
                                               const float* __restrict__ mask) {
    int bid = blockIdx.x;
    int t = threadIdx.x;
    if (bid < 4096) {
        __shared__ u16 lk[2048];
        // coalesced read: thread t covers bytes t*32..t*32+31 of the 8KB f32 block
        int bh = bid >> 5, j = bid & 31;
        int row = t >> 3, dg = t & 7;
        const float* s = k + ((size_t)(bh * SEQ + j * 32 + row)) * HD + dg * 8;
        float4 a = *(const float4*)(s);
        float4 b = *(const float4*)(s + 4);
        bf16x8 hi = pack8(a, b);
        int c = ((row >> 4) << 1) + (dg >> 2);
        int lane = (row & 15) + ((dg & 3) << 4);
        *(bf16x8_a*)(&lk[c * 512 + lane * 8]) = hi;
        __syncthreads();
        // coalesced store: thread t writes flat elems t*8
        u16* dst = g_pack + ((size_t)(bh * NB + j)) * PBLK + t * 8;
        *(uint4*)dst = *(const uint4*)&lk[t * 8];
        return;
    }
    if (bid < 6144) {
        __shared__ float tile[32 * 65];
        // V transpose + bf16, A-fragment order: A[d = c*16 + (lane&15)][key = (lane>>4)*8 + e]
        int tb = bid - 4096;                      // 2048 = 128 bh * 16 ktiles(64)
        int bh = tb >> 4, kt = tb & 15;
        const float* src = v + ((size_t)(bh * SEQ + kt * 64)) * HD;
#pragma unroll
        for (int pass = 0; pass < 2; ++pass) {
#pragma unroll
            for (int p = 0; p < 2; ++p) {
                int row = p * 16 + (t >> 4);              // 0..31 within pass
                int col = (t & 15) * 4;
                float4 d = *(const float4*)(src + (size_t)(pass * 32 + row) * HD + col);
                float* tp = &tile[row * 65 + col];
                tp[0] = d.x; tp[1] = d.y; tp[2] = d.z; tp[3] = d.w;
            }
            __syncthreads();
            {
                // coalesced store map: thread t -> flat elem t*8 of the V^T section.
                int c = t >> 6;
                int lane = t & 63;
                int dd = (c << 4) + (lane & 15);
                int kc = (lane >> 4) * 8;
                u16 tmp[8];
#pragma unroll
                for (int i = 0; i < 8; ++i) tmp[i] = f2bf(tile[(kc + i) * 65 + dd]);
                int j = kt * 2 + pass;
                size_t o = ((size_t)(bh * NB + j)) * PBLK + 2048 + (size_t)t * 8;
                *(uint4*)(g_pack + o) = *(const uint4*)tmp;
            }
            __syncthreads();
        }
        return;
    }
    // block-mask path: 16 blocks, one head each; 256 threads sweep 1024 (i,j) pairs
    int h = bid - 6144;
    int lane = t & 63;
#pragma unroll
    for (int kk2 = 0; kk2 < 4; ++kk2) {
        int tt = (kk2 << 8) | t;                  // 0..1023
        int i = tt >> 5, j = tt & 31;
        float mv = mask[(size_t)h * SEQ * SEQ + (size_t)(i * 32) * SEQ + (size_t)(j * 32)];
        bool pred = (j == i) || (j < i && mv != 0.0f);
        unsigned long long bal = __ballot(pred);
        if (lane == 0)  g_bm[h * NB + i] = (unsigned)(bal & 0xffffffffull);
        if (lane == 32) g_bm[h * NB + i] = (unsigned)(bal >> 32);
    }
}

// ---------------- attention building blocks ----------------
__device__ __forceinline__ void load_blk(size_t pb, bf16x8 (&kh)[4], bf16x8 (&vf)[4]) {
#pragma unroll
    for (int c = 0; c < 4; ++c) {
        kh[c] = *(const bf16x8_a*)(const void*)(g_pack + pb + c * 512);
        vf[c] = *(const bf16x8_a*)(const void*)(g_pack + pb + 2048 + c * 512);
    }
}

__device__ __forceinline__ void compute_blk(int j, int i32, int qcol, int quad,
                                            const bf16x8 (&kh)[4], const bf16x8 (&vf)[4],
                                            const bf16x8 (&qh)[2][2], const bf16x8 (&ql)[2][2],
                                            u16* pl, f32x4 (&oacc)[2][4], float& l0, float& l1) {
    // T = K*Q^T, K single bf16 + Q hi/lo split; tt[kt][t]: keys kt*16+quad*4+r, q = t*16+qcol
    f32x4 tt[2][2];
    __builtin_amdgcn_s_setprio(1);
#pragma unroll
    for (int kt = 0; kt < 2; ++kt)
#pragma unroll
        for (int t = 0; t < 2; ++t) {
            f32x4 acc = f32x4{0.f, 0.f, 0.f, 0.f};
            acc = __builtin_amdgcn_mfma_f32_16x16x32_bf16(kh[kt*2+0], ql[t][0], acc, 0, 0, 0);
            acc = __builtin_amdgcn_mfma_f32_16x16x32_bf16(kh[kt*2+1], ql[t][1], acc, 0, 0, 0);
            acc = __builtin_amdgcn_mfma_f32_16x16x32_bf16(kh[kt*2+0], qh[t][0], acc, 0, 0, 0);
            acc = __builtin_amdgcn_mfma_f32_16x16x32_bf16(kh[kt*2+1], qh[t][1], acc, 0, 0, 0);
            tt[kt][t] = acc;
        }
    __builtin_amdgcn_s_setprio(0);

    if (j == i32) {  // diagonal block: causal within 32x32
#pragma unroll
        for (int kt = 0; kt < 2; ++kt)
#pragma unroll
            for (int t = 0; t < 2; ++t)
#pragma unroll
                for (int r = 0; r < 4; ++r) {
                    int key = kt * 16 + quad * 4 + r;
                    if (key > t * 16 + qcol) tt[kt][t][r] = -1e30f;
                }
    }

    // static-max softmax: p = exp2(s*log2e - 32*log2e); no reductions in loop
    u16 pb[2][8];
#pragma unroll
    for (int kt = 0; kt < 2; ++kt)
#pragma unroll
        for (int t = 0; t < 2; ++t) {
            float psum = 0.f;
#pragma unroll
            for (int r = 0; r < 4; ++r) {
                float e = exp2f(tt[kt][t][r] * LOG2E - MBIAS);
                u16 eb = f2bf(e);
                pb[t][kt * 4 + r] = eb;
                psum += bf2f(eb);      // sum ROUNDED p: out = sum(p_hat v)/sum(p_hat)
            }
            if (t == 0) l0 += psum; else l1 += psum;
        }

    // P^T relayout through LDS (same-wave DS ops in order; may_alias preserves ordering)
#pragma unroll
    for (int t = 0; t < 2; ++t)
#pragma unroll
        for (int kt = 0; kt < 2; ++kt) {
            u32x2 pw;
            pw[0] = (unsigned)pb[t][kt*4+0] | ((unsigned)pb[t][kt*4+1] << 16);
            pw[1] = (unsigned)pb[t][kt*4+2] | ((unsigned)pb[t][kt*4+3] << 16);
            *(u32x2_a*)(pl + (t * 16 + qcol) * 40 + kt * 16 + quad * 4) = pw;
        }
    bf16x8 pf0 = *(const bf16x8_a*)(pl + qcol * 40 + quad * 8);
    bf16x8 pf1 = *(const bf16x8_a*)(pl + (16 + qcol) * 40 + quad * 8);

    __builtin_amdgcn_s_setprio(1);
#pragma unroll
    for (int c = 0; c < 4; ++c) {
        oacc[0][c] = __builtin_amdgcn_mfma_f32_16x16x32_bf16(vf[c], pf0, oacc[0][c], 0, 0, 0);
        oacc[1][c] = __builtin_amdgcn_mfma_f32_16x16x32_bf16(vf[c], pf1, oacc[1][c], 0, 0, 0);
    }
    __builtin_amdgcn_s_setprio(0);
}

// ---------------- block-sparse causal flash attention ----------------
// r10 structure (best measured attn: 42.0us), with 8KB visits (K-lo dropped).
// ONE WAVE per (bh, i32) row-block, 4096 independent 64-thread blocks.
// Dispatch: slot = bid&7 == bh&7 pins bh to one XCD (r1: 3x traffic without);
// two 8-bh half-groups per XCD; i32 descending (heavy-first LPT).
__global__ __launch_bounds__(64, 2) void attn(const float* __restrict__ q,
                                              float* __restrict__ out) {
    __shared__ __align__(16) char smem[8704];   // P relayout (first 2560B) / O staging union

    int lane = threadIdx.x & 63;
    int qcol = lane & 15;
    int quad = lane >> 4;

    int bid = blockIdx.x;
    int slot = bid & 7;                 // XCD
    int r = bid >> 3;                   // 0..511 per slot
    int half = r >> 8;                  // 8-bh group
    int rr = r & 255;
    int i32 = 31 - (rr >> 3);           // heavy rows dispatched first within group
    int bh = slot + ((((half << 3) | (rr & 7))) << 3);   // bh&7 == slot
    int h = bh & (HEADS - 1);

    // Q fragments (B-operand): X[q=qcol][d = quad*8 + dh*32 + e], per q-tile t
    bf16x8 qh[2][2], ql[2][2];
#pragma unroll
    for (int t = 0; t < 2; ++t) {
        const float* qb = q + ((size_t)(bh * SEQ + i32 * 32 + t * 16 + qcol)) * HD + quad * 8;
#pragma unroll
        for (int dh = 0; dh < 2; ++dh) {
            float4 a = *(const float4*)(qb + dh * 32);
            float4 b = *(const float4*)(qb + dh * 32 + 4);
            qh[t][dh] = pack8(a, b);
            ql[t][dh] = pack8_res(a, b, qh[t][dh]);
        }
    }

    unsigned bits = g_bm[h * NB + i32];
    size_t bhbase = (size_t)bh * NB * PBLK + lane * 8;
    u16* pl = (u16*)smem;

    f32x4 oacc[2][4];
#pragma unroll
    for (int t = 0; t < 2; ++t)
#pragma unroll
        for (int c = 0; c < 4; ++c) oacc[t][c] = f32x4{0.f, 0.f, 0.f, 0.f};
    float l0 = 0.f, l1 = 0.f;

    // software-pipelined loop: issue next block's frag loads before computing current
    bf16x8 khA[4], vfA[4], khB[4], vfB[4];
    unsigned rem = bits;
    if (rem) {
        int jA = __builtin_ctz(rem); rem &= rem - 1;
        load_blk(bhbase + (size_t)jA * PBLK, khA, vfA);
        for (;;) {
            int jB = -1;
            if (rem) { jB = __builtin_ctz(rem); rem &= rem - 1;
                       load_blk(bhbase + (size_t)jB * PBLK, khB, vfB); }
            compute_blk(jA, i32, qcol, quad, khA, vfA, qh, ql, pl, oacc, l0, l1);
            if (jB < 0) break;
            jA = -1;
            if (rem) { jA = __builtin_ctz(rem); rem &= rem - 1;
                       load_blk(bhbase + (size_t)jA * PBLK, khA, vfA); }
            compute_blk(jB, i32, qcol, quad, khB, vfB, qh, ql, pl, oacc, l0, l1);
            if (jA < 0) break;
        }
    }

    // l reduction: after butterfly, l0/l1 hold the per-q-row denominator (per qcol)
    l0 += __shfl_xor(l0, 16); l0 += __shfl_xor(l0, 32);
    l1 += __shfl_xor(l1, 16); l1 += __shfl_xor(l1, 32);
    float inv[2] = {1.0f / l0, 1.0f / l1};

    // O = oacc / l staged via LDS for dense 1KB stores (same-wave DS ordering)
    float* ol = (float*)smem;             // 32 rows x 64 d, stride 68 floats
#pragma unroll
    for (int t = 0; t < 2; ++t)
#pragma unroll
        for (int c = 0; c < 4; ++c) {
            f32x4 val;
            val[0] = oacc[t][c][0] * inv[t]; val[1] = oacc[t][c][1] * inv[t];
            val[2] = oacc[t][c][2] * inv[t]; val[3] = oacc[t][c][3] * inv[t];
            *(f32x4_a*)(ol + (t * 16 + qcol) * 68 + c * 16 + quad * 4) = val;
        }
    // dense output: per instr 64 lanes cover 4 rows x 256B = 1KB contiguous
    float* obase = out + ((size_t)(bh * SEQ + i32 * 32)) * HD;
#pragma unroll
    for (int gr = 0; gr < 8; ++gr) {
        int row = gr * 4 + (lane >> 4);
        int colf = (lane & 15) * 4;
        f32x4 val = *(const f32x4_a*)(ol + row * 68 + colf);
        *(float4*)(obase + (size_t)row * HD + colf) = make_float4(val[0], val[1], val[2], val[3]);
    }
}

extern "C" void kernel_launch(void* const* d_in, const int* in_sizes, int n_in,
                              void* d_out, int out_size, void* d_ws, size_t ws_size,
                              hipStream_t stream) {
    const float* q = (const float*)d_in[0];
    const float* k = (const float*)d_in[1];
    const float* v = (const float*)d_in[2];
    const float* mask = (const float*)d_in[3];
    float* out = (float*)d_out;

    prep_kv<<<4096 + 2048 + 16, 256, 0, stream>>>(k, v, mask);
    attn<<<4096, 64, 0, stream>>>(q, out);
}